// Round 1
// baseline (778.414 us; speedup 1.0000x reference)
//
#include <hip/hip_runtime.h>
#include <math.h>

// Problem constants (from reference)
#define VOCABN 8192
#define EMBN   80
#define UNITSN 2048
#define BATCHN 64
#define SEQN   64

typedef _Float16 f16;
typedef _Float16 f16x8 __attribute__((ext_vector_type(8)));
typedef float    f32x4 __attribute__((ext_vector_type(4)));

// LDS geometry: B-operand slice [32 uu][2176 k] f16, XOR-swizzled rows.
#define BROW 4352  // bytes per uu row (2176 halves); multiple of 256 for swizzle safety

// ws layout (bytes):
//   [0, 524288)          : hbuf, 2 x [64][2048] f16 (double-buffered h0 state)
//   [524288, 525312)     : cnt, 4 groups x 64 steps int arrival counters
//   [525312, 525568)     : out_pre, 64 floats (pre-sigmoid accumulators)
#define HBUF_BYTES   (2 * BATCHN * UNITSN * 2)
#define CNT_OFF      HBUF_BYTES
#define OUTPRE_OFF   (CNT_OFF + 4 * SEQN * 4)
#define WS_ZERO_B    (OUTPRE_OFF + BATCHN * 4)

// ---------------------------------------------------------------------------
// Recurrent kernel: 256 WGs = 4 row-groups (16 batch rows) x 64 col-chunks (32 cols).
// Wh0 slice (f16) + Wx0 slice live in LDS for all 64 steps. Per step:
// stage x_t -> MFMA (h@Wh0 + x@Wx0, K split over 4 waves) -> LDS reduce ->
// tanh -> f16 store (agent scope) -> group barrier via per-step counters.
// ---------------------------------------------------------------------------
__global__ __launch_bounds__(256)
void rnn_recur(const int* __restrict__ inputs, const float* __restrict__ emb,
               const float* __restrict__ Wx, const float* __restrict__ Wh,
               const float* __restrict__ bias, f16* __restrict__ hbuf,
               int* __restrict__ cnt)
{
    __shared__ unsigned char Blds[32 * BROW];   // 139264 B: [uu][k] f16, swizzled
    __shared__ f16  xlds[16][136];              // x_t staging, f16, padded stride
    __shared__ float red[4][2][64][4];          // per-wave MFMA partials
    __shared__ int  idxlds[16][SEQN];           // token ids for this row group

    const int tid = threadIdx.x;
    const int wg  = blockIdx.x;
    const int g   = wg >> 6;           // row group 0..3 (batch rows 16g..16g+15)
    const int c0  = (wg & 63) * 32;    // output column base
    const int g16 = g * 16;

    // token indices for the group's 16 rows, all timesteps
    for (int i = tid; i < 16 * SEQN; i += 256)
        idxlds[i >> 6][i & 63] = inputs[(g16 + (i >> 6)) * SEQN + (i & 63)];

    // Load Wh0 [2048 x 32] and Wx0 [80->96 x 32] slices, fp32 -> f16, into
    // swizzled LDS: byte = uu*BROW + ((2k) ^ ((uu&15)<<4)).
    {
        const int j0 = tid >> 3, l8 = tid & 7;
        for (int it = 0; it < 64; ++it) {
            const int j = j0 + it * 32;
            const float4 w = *(const float4*)(Wh + (size_t)j * UNITSN + c0 + l8 * 4);
            const float vals[4] = {w.x, w.y, w.z, w.w};
#pragma unroll
            for (int q = 0; q < 4; ++q) {
                const int uu = l8 * 4 + q;
                *(f16*)(Blds + uu * BROW + ((2 * j) ^ ((uu & 15) << 4))) = (f16)vals[q];
            }
        }
        for (int j2 = j0; j2 < 96; j2 += 32) {   // x-part rows at k = 2048+j2, zero-padded
            float vals[4] = {0.f, 0.f, 0.f, 0.f};
            if (j2 < EMBN) {
                const float4 w = *(const float4*)(Wx + (size_t)j2 * UNITSN + c0 + l8 * 4);
                vals[0] = w.x; vals[1] = w.y; vals[2] = w.z; vals[3] = w.w;
            }
#pragma unroll
            for (int q = 0; q < 4; ++q) {
                const int uu = l8 * 4 + q;
                const int k = 2048 + j2;
                *(f16*)(Blds + uu * BROW + ((2 * k) ^ ((uu & 15) << 4))) = (f16)vals[q];
            }
        }
    }
    __syncthreads();

    const int lane = tid & 63;
    const int wv   = tid >> 6;      // wave 0..3: K-split
    const int l16  = lane & 15;
    const int lq   = lane >> 4;
    // reduction-phase coordinates: thread -> outputs (rr, cpa) and (rr, cpa+1)
    const int rr  = tid >> 4;
    const int cpa = (tid & 15) * 2;
    const float ba = bias[c0 + cpa];
    const float bb = bias[c0 + cpa + 1];
    const int tla = cpa >> 4;
    const int la  = ((rr >> 2) << 4) + (cpa & 15);
    const int rg  = rr & 3;

    for (int t = 0; t < SEQN; ++t) {
        const int p = t & 1;   // read buf p, write buf p^1
        // stage x_t (embedding gather) into xlds, f16
        {
            const int r  = tid >> 4;
            const int kb = (tid & 15) * 6;
            const float* erow = emb + (size_t)idxlds[r][t] * EMBN;
#pragma unroll
            for (int q = 0; q < 6; ++q) {
                const int k = kb + q;
                xlds[r][k] = (f16)((k < EMBN) ? erow[k] : 0.f);
            }
        }
        __syncthreads();

        // MFMA: acc[16x32] = h_prev @ Wh0_slice + x_t @ Wx0_slice (K split by wave)
        f32x4 acc0 = {0.f, 0.f, 0.f, 0.f};
        f32x4 acc1 = {0.f, 0.f, 0.f, 0.f};
        {
            const f16* hrow = hbuf + (size_t)p * BATCHN * UNITSN + (size_t)(g16 + l16) * UNITSN;
            const int swz = (l16 & 15) << 4;   // uu0&15 == uu1&15 == l16
            const unsigned char* brow0 = Blds + l16 * BROW;
            const unsigned char* brow1 = Blds + (16 + l16) * BROW;
#pragma unroll 4
            for (int kk = wv * 16; kk < wv * 16 + 16; ++kk) {
                const int k0 = kk * 32 + lq * 8;
                const f16x8 av  = *(const f16x8*)(hrow + k0);
                const int   bo  = (2 * k0) ^ swz;
                const f16x8 bv0 = *(const f16x8*)(brow0 + bo);
                const f16x8 bv1 = *(const f16x8*)(brow1 + bo);
                acc0 = __builtin_amdgcn_mfma_f32_16x16x32_f16(av, bv0, acc0, 0, 0, 0);
                acc1 = __builtin_amdgcn_mfma_f32_16x16x32_f16(av, bv1, acc1, 0, 0, 0);
            }
            if (wv < 3) {   // x-part K-slices (k = 2048..2143), one per wave 0..2
                const int kx0 = wv * 32 + lq * 8;
                const int k0  = 2048 + kx0;
                const f16x8 av  = *(const f16x8*)(&xlds[l16][kx0]);
                const int   bo  = (2 * k0) ^ swz;
                const f16x8 bv0 = *(const f16x8*)(brow0 + bo);
                const f16x8 bv1 = *(const f16x8*)(brow1 + bo);
                acc0 = __builtin_amdgcn_mfma_f32_16x16x32_f16(av, bv0, acc0, 0, 0, 0);
                acc1 = __builtin_amdgcn_mfma_f32_16x16x32_f16(av, bv1, acc1, 0, 0, 0);
            }
        }
        *(f32x4*)(&red[wv][0][lane][0]) = acc0;
        *(f32x4*)(&red[wv][1][lane][0]) = acc1;
        __syncthreads();

        // reduce 4 waves, add bias, tanh, pack 2 x f16, agent-scope store
        {
            float va = ba, vb = bb;
#pragma unroll
            for (int w = 0; w < 4; ++w) {
                va += red[w][tla][la][rg];
                vb += red[w][tla][la + 1][rg];
            }
            const f16 ha = (f16)tanhf(va);
            const f16 hb = (f16)tanhf(vb);
            const unsigned int pk = (unsigned int)__builtin_bit_cast(unsigned short, ha)
                                  | ((unsigned int)__builtin_bit_cast(unsigned short, hb) << 16);
            unsigned int* dst = (unsigned int*)(hbuf + (size_t)(p ^ 1) * BATCHN * UNITSN
                                                + (size_t)(g16 + rr) * UNITSN + c0 + cpa);
            __hip_atomic_store(dst, pk, __ATOMIC_RELAXED, __HIP_MEMORY_SCOPE_AGENT);
        }
        __syncthreads();   // drains vmcnt -> all h stores at coherence point

        // group barrier: 64 WGs of group g, per-step counter (memset 0 each launch)
        if (tid == 0) {
            int* flag = cnt + g * SEQN + t;
            __hip_atomic_fetch_add(flag, 1, __ATOMIC_RELEASE, __HIP_MEMORY_SCOPE_AGENT);
            int spins = 0;
            while (__hip_atomic_load(flag, __ATOMIC_ACQUIRE, __HIP_MEMORY_SCOPE_AGENT) < 64) {
                __builtin_amdgcn_s_sleep(2);
                if (++spins > 2000000) break;   // safety valve (never hit normally)
            }
        }
        __syncthreads();
    }
}

// ---------------------------------------------------------------------------
// Final layer-5 at t=63: h5 = tanh(x63@Wx5 + h0_final@Wh5 + b5); accumulate
// h5 . Wout into out_pre[b] via atomics. 256 WGs = 4 row-groups x 64 col-chunks.
// ---------------------------------------------------------------------------
__global__ __launch_bounds__(256)
void final_layer(const int* __restrict__ inputs, const float* __restrict__ emb,
                 const float* __restrict__ Wx, const float* __restrict__ Wh,
                 const float* __restrict__ bias, const float* __restrict__ Wout,
                 const f16* __restrict__ hbuf, float* __restrict__ out_pre)
{
    __shared__ float red[16][16];
    const int tid = threadIdx.x;
    const int wg  = blockIdx.x;
    const int g   = wg >> 6;
    const int c0  = (wg & 63) * 32;
    const int rr  = tid >> 4;
    const int cl  = tid & 15;
    const int b   = g * 16 + rr;
    const int cola = c0 + cl;         // coalesced halves
    const int colb = cola + 16;

    const float* Wh5 = Wh + (size_t)5 * UNITSN * UNITSN;
    const float* Wx5 = Wx + (size_t)5 * EMBN * UNITSN;
    const float* b5  = bias + 5 * UNITSN;

    float acc0 = b5[cola], acc1 = b5[colb];
    {
        const float* erow = emb + (size_t)inputs[b * SEQN + SEQN - 1] * EMBN;
        for (int k = 0; k < EMBN; ++k) {
            const float xv = erow[k];
            acc0 = fmaf(xv, Wx5[(size_t)k * UNITSN + cola], acc0);
            acc1 = fmaf(xv, Wx5[(size_t)k * UNITSN + colb], acc1);
        }
    }
    const f16* h0 = hbuf + (size_t)b * UNITSN;   // final h0 is in buffer 0
#pragma unroll 4
    for (int j = 0; j < UNITSN; ++j) {
        const float hv = (float)h0[j];
        acc0 = fmaf(hv, Wh5[(size_t)j * UNITSN + cola], acc0);
        acc1 = fmaf(hv, Wh5[(size_t)j * UNITSN + colb], acc1);
    }
    const float h5a = tanhf(acc0), h5b = tanhf(acc1);
    red[rr][cl] = h5a * Wout[cola] + h5b * Wout[colb];
    __syncthreads();
    if (tid < 16) {
        float s = 0.f;
#pragma unroll
        for (int i = 0; i < 16; ++i) s += red[tid][i];
        atomicAdd(&out_pre[g * 16 + tid], s);
    }
}

__global__ void final_out(const float* __restrict__ out_pre,
                          const float* __restrict__ bout, float* __restrict__ out)
{
    const int b = threadIdx.x;
    if (b < BATCHN) out[b] = 1.f / (1.f + expf(-(out_pre[b] + bout[0])));
}

// ---------------------------------------------------------------------------
extern "C" void kernel_launch(void* const* d_in, const int* in_sizes, int n_in,
                              void* d_out, int out_size, void* d_ws, size_t ws_size,
                              hipStream_t stream) {
    (void)in_sizes; (void)n_in; (void)out_size; (void)ws_size;
    const int*   inputs = (const int*)d_in[0];
    const float* emb    = (const float*)d_in[1];
    const float* Wx     = (const float*)d_in[2];
    const float* Wh     = (const float*)d_in[3];
    const float* bias   = (const float*)d_in[4];
    const float* Wout   = (const float*)d_in[5];
    const float* bout   = (const float*)d_in[6];
    float* out = (float*)d_out;

    f16*   hbuf    = (f16*)d_ws;
    int*   cnt     = (int*)((char*)d_ws + CNT_OFF);
    float* out_pre = (float*)((char*)d_ws + OUTPRE_OFF);

    // reset h state, barrier counters, output accumulators (replay-deterministic)
    hipMemsetAsync(d_ws, 0, WS_ZERO_B, stream);

    // Cooperative launch when possible (residency guarantee for the spin
    // barrier); inside graph capture use a plain launch (256 WGs at 1 WG/CU on
    // 256 CUs are co-resident by construction).
    hipStreamCaptureStatus cs = hipStreamCaptureStatusNone;
    hipStreamIsCapturing(stream, &cs);
    if (cs == hipStreamCaptureStatusActive) {
        rnn_recur<<<dim3(256), dim3(256), 0, stream>>>(inputs, emb, Wx, Wh, bias, hbuf, cnt);
    } else {
        void* args[] = {(void*)&inputs, (void*)&emb, (void*)&Wx, (void*)&Wh,
                        (void*)&bias, (void*)&hbuf, (void*)&cnt};
        hipError_t e = hipLaunchCooperativeKernel((const void*)rnn_recur, dim3(256), dim3(256),
                                                  args, 0, stream);
        if (e != hipSuccess) {
            rnn_recur<<<dim3(256), dim3(256), 0, stream>>>(inputs, emb, Wx, Wh, bias, hbuf, cnt);
        }
    }
    final_layer<<<dim3(256), dim3(256), 0, stream>>>(inputs, emb, Wx, Wh, bias, Wout, hbuf, out_pre);
    final_out<<<dim3(1), dim3(64), 0, stream>>>(out_pre, bout, out);
}

// Round 2
// 581.861 us; speedup vs baseline: 1.3378x; 1.3378x over previous
//
#include <hip/hip_runtime.h>
#include <math.h>

// Problem constants (from reference)
#define VOCABN 8192
#define EMBN   80
#define UNITSN 2048
#define BATCHN 64
#define SEQN   64

typedef _Float16 f16;
typedef _Float16 f16x8 __attribute__((ext_vector_type(8)));
typedef float    f32x4 __attribute__((ext_vector_type(4)));

// LDS geometry: B-operand slice [32 uu][2176 k] f16, XOR-swizzled rows.
#define BROW 4352  // bytes per uu row; padded so swizzle stays in-row

// ws layout (bytes):
//   [0, 524288)          : hbuf, 2 x [64][2048] f16 (double-buffered h0 state)
//   [524288, 525312)     : flags, 4 groups x 64 WG monotonic step counters
//   [525312, 525568)     : out_pre, 64 floats (pre-sigmoid accumulators)
#define HBUF_BYTES   (2 * BATCHN * UNITSN * 2)
#define FLAGS_OFF    HBUF_BYTES
#define OUTPRE_OFF   (FLAGS_OFF + 4 * 64 * 4)
#define WS_ZERO_B    (OUTPRE_OFF + BATCHN * 4)

__device__ __forceinline__ f32x4 mfma16(f16x8 a, f16x8 b, f32x4 c) {
    return __builtin_amdgcn_mfma_f32_16x16x32_f16(a, b, c, 0, 0, 0);
}

// Load cols [c0,c0+32) of W [2048 x 2048] (+ Wxp [80 x 2048] at k=2048..2143,
// zero-padded to 2144) as f16 into swizzled LDS: byte = uu*BROW + ((2k)^((uu&15)<<4)).
__device__ __forceinline__ void load_wslice(const float* __restrict__ W,
                                            const float* __restrict__ Wxp,
                                            int c0, int tid, unsigned char* Blds)
{
    const int j0 = tid >> 3, l8 = tid & 7;
    for (int it = 0; it < 64; ++it) {
        const int j = j0 + it * 32;
        const float4 w = *(const float4*)(W + (size_t)j * UNITSN + c0 + l8 * 4);
        const float vals[4] = {w.x, w.y, w.z, w.w};
#pragma unroll
        for (int q = 0; q < 4; ++q) {
            const int uu = l8 * 4 + q;
            *(f16*)(Blds + uu * BROW + ((2 * j) ^ ((uu & 15) << 4))) = (f16)vals[q];
        }
    }
    for (int j2 = j0; j2 < 96; j2 += 32) {
        float vals[4] = {0.f, 0.f, 0.f, 0.f};
        if (j2 < EMBN) {
            const float4 w = *(const float4*)(Wxp + (size_t)j2 * UNITSN + c0 + l8 * 4);
            vals[0] = w.x; vals[1] = w.y; vals[2] = w.z; vals[3] = w.w;
        }
#pragma unroll
        for (int q = 0; q < 4; ++q) {
            const int uu = l8 * 4 + q;
            const int k = 2048 + j2;
            *(f16*)(Blds + uu * BROW + ((2 * k) ^ ((uu & 15) << 4))) = (f16)vals[q];
        }
    }
}

// ---------------------------------------------------------------------------
// Recurrent kernel: 256 WGs = 4 row-groups (16 batch rows) x 64 col-chunks.
// Barrier v2: per-WG monotonic flag slots (release store), wave-0 vectorized
// relaxed poll + one acquire fence, x_{t+1} staged during the wait.
// ---------------------------------------------------------------------------
__global__ __launch_bounds__(256)
void rnn_recur(const int* __restrict__ inputs, const float* __restrict__ emb,
               const float* __restrict__ Wx, const float* __restrict__ Wh,
               const float* __restrict__ bias, f16* __restrict__ hbuf,
               int* __restrict__ flags)
{
    __shared__ unsigned char Blds[32 * BROW];   // 139264 B
    __shared__ f16  xlds[2][16][96];            // 6144 B, double-buffered x_t
    __shared__ float red[4][2][64][4];          // 8192 B, per-wave MFMA partials
    __shared__ int  idxlds[16][SEQN];           // 4096 B, token ids

    const int tid = threadIdx.x;
    const int wg  = blockIdx.x;
    const int g     = wg >> 6;          // row group 0..3
    const int wslot = wg & 63;          // this WG's flag slot within group
    const int c0  = wslot * 32;         // output column base
    const int g16 = g * 16;

    for (int i = tid; i < 16 * SEQN; i += 256)
        idxlds[i >> 6][i & 63] = inputs[(g16 + (i >> 6)) * SEQN + (i & 63)];

    load_wslice(Wh, Wx, c0, tid, Blds);
    __syncthreads();

    // stage x_0
    {
        const int r  = tid >> 4;
        const int kb = (tid & 15) * 6;
        const float* erow = emb + (size_t)idxlds[r][0] * EMBN;
#pragma unroll
        for (int q = 0; q < 6; ++q) {
            const int k = kb + q;
            xlds[0][r][k] = (f16)((k < EMBN) ? erow[k] : 0.f);
        }
    }
    __syncthreads();

    const int lane = tid & 63;
    const int wv   = tid >> 6;      // wave 0..3: K-split
    const int l16  = lane & 15;
    const int lq   = lane >> 4;
    const int rr  = tid >> 4;       // reduce-phase output row 0..15
    const int cpa = (tid & 15) * 2; // reduce-phase output col pair
    const float ba = bias[c0 + cpa];
    const float bb = bias[c0 + cpa + 1];
    const int tla = cpa >> 4;
    const int la  = ((rr >> 2) << 4) + (cpa & 15);
    const int rg  = rr & 3;

    int* gflags = flags + g * 64;

    for (int t = 0; t < SEQN; ++t) {
        const int p = t & 1;   // read buf p, write buf p^1

        // MFMA: acc[16x32] = h_prev @ Wh0 + x_t @ Wx0 (K split by wave);
        // A-fragment loads hoisted so all IF-latency loads are in flight.
        f32x4 acc0 = {0.f, 0.f, 0.f, 0.f};
        f32x4 acc1 = {0.f, 0.f, 0.f, 0.f};
        {
            const f16* hrow = hbuf + (size_t)p * BATCHN * UNITSN
                            + (size_t)(g16 + l16) * UNITSN + wv * 512 + lq * 8;
            const int swz = l16 << 4;
            const unsigned char* brow0 = Blds + l16 * BROW;
            const unsigned char* brow1 = Blds + (16 + l16) * BROW;
            f16x8 av[16];
#pragma unroll
            for (int kk = 0; kk < 16; ++kk)
                av[kk] = *(const f16x8*)(hrow + kk * 32);
            f16x8 ax;
            if (wv < 3) ax = *(const f16x8*)(&xlds[p][l16][wv * 32 + lq * 8]);
#pragma unroll
            for (int kk = 0; kk < 16; ++kk) {
                const int k0 = wv * 512 + kk * 32 + lq * 8;
                const int bo = (2 * k0) ^ swz;
                acc0 = mfma16(av[kk], *(const f16x8*)(brow0 + bo), acc0);
                acc1 = mfma16(av[kk], *(const f16x8*)(brow1 + bo), acc1);
            }
            if (wv < 3) {
                const int k0 = 2048 + wv * 32 + lq * 8;
                const int bo = (2 * k0) ^ swz;
                acc0 = mfma16(ax, *(const f16x8*)(brow0 + bo), acc0);
                acc1 = mfma16(ax, *(const f16x8*)(brow1 + bo), acc1);
            }
        }
        *(f32x4*)(&red[wv][0][lane][0]) = acc0;
        *(f32x4*)(&red[wv][1][lane][0]) = acc1;
        __syncthreads();

        // reduce 4 waves, bias, tanh, agent-scope packed store
        {
            float va = ba, vb = bb;
#pragma unroll
            for (int w = 0; w < 4; ++w) {
                va += red[w][tla][la][rg];
                vb += red[w][tla][la + 1][rg];
            }
            const f16 ha = (f16)tanhf(va);
            const f16 hb = (f16)tanhf(vb);
            const unsigned int pk = (unsigned int)__builtin_bit_cast(unsigned short, ha)
                                  | ((unsigned int)__builtin_bit_cast(unsigned short, hb) << 16);
            unsigned int* dst = (unsigned int*)(hbuf + (size_t)(p ^ 1) * BATCHN * UNITSN
                                                + (size_t)(g16 + rr) * UNITSN + c0 + cpa);
            __hip_atomic_store(dst, pk, __ATOMIC_RELAXED, __HIP_MEMORY_SCOPE_AGENT);
        }
        __syncthreads();   // drains vmcnt in every wave -> all h stores visible

        if (t == SEQN - 1) break;   // final h0 now in hbuf[0]; no barrier needed

        // publish: own slot, monotonic value, release
        if (tid == 0)
            __hip_atomic_store(&gflags[wslot], t + 1, __ATOMIC_RELEASE,
                               __HIP_MEMORY_SCOPE_AGENT);

        // overlap: stage x_{t+1} while the flags converge
        {
            const int r  = tid >> 4;
            const int kb = (tid & 15) * 6;
            const float* erow = emb + (size_t)idxlds[r][t + 1] * EMBN;
            const int buf = (t + 1) & 1;
#pragma unroll
            for (int q = 0; q < 6; ++q) {
                const int k = kb + q;
                xlds[buf][r][k] = (f16)((k < EMBN) ? erow[k] : 0.f);
            }
        }

        // wave-0 vectorized poll: one 64-lane relaxed load per round, no inv
        if (wv == 0) {
            int tries = 0;
            for (;;) {
                const int v = __hip_atomic_load(&gflags[lane], __ATOMIC_RELAXED,
                                                __HIP_MEMORY_SCOPE_AGENT);
                if (__all(v > t)) break;
                __builtin_amdgcn_s_sleep(1);
                if (++tries > 300000) break;   // safety valve
            }
            __builtin_amdgcn_fence(__ATOMIC_ACQUIRE, "agent");  // one inv per step
        }
        __syncthreads();   // releases waves 1..3; xlds[t+1] also ready
    }
}

// ---------------------------------------------------------------------------
// Final layer-5 at t=63 via MFMA: 64 WGs, each 32 cols x all 64 batch rows.
// h5 = tanh(x63@Wx5 + h0@Wh5 + b5); out_pre[r] += h5 . Wout (atomicAdd).
// ---------------------------------------------------------------------------
__global__ __launch_bounds__(256)
void final_gemm(const int* __restrict__ inputs, const float* __restrict__ emb,
                const float* __restrict__ Wx, const float* __restrict__ Wh,
                const float* __restrict__ bias, const float* __restrict__ Wout,
                const f16* __restrict__ hbuf, float* __restrict__ out_pre)
{
    __shared__ unsigned char Blds[32 * BROW];   // 139264 B
    __shared__ f16  xlds[64][96];               // 12288 B
    __shared__ float red[4][64][4];             // 4096 B (one col-tile pass)
    __shared__ float rowacc[64][4];             // 1024 B

    const int tid = threadIdx.x;
    const int c0  = blockIdx.x * 32;
    const float* Wh5 = Wh + (size_t)5 * UNITSN * UNITSN;
    const float* Wx5 = Wx + (size_t)5 * EMBN * UNITSN;
    const float* b5  = bias + 5 * UNITSN;

    load_wslice(Wh5, Wx5, c0, tid, Blds);
    // stage x_63 for all 64 rows
    {
        const int r  = tid >> 2;
        const int kb = (tid & 3) * 24;
        const float* erow = emb + (size_t)inputs[r * SEQN + SEQN - 1] * EMBN;
#pragma unroll
        for (int q = 0; q < 24; ++q) {
            const int k = kb + q;
            xlds[r][k] = (f16)((k < EMBN) ? erow[k] : 0.f);
        }
    }
    rowacc[tid >> 2][tid & 3] = 0.f;
    __syncthreads();

    const int lane = tid & 63;
    const int wv   = tid >> 6;
    const int l16  = lane & 15;
    const int lq   = lane >> 4;

    for (int ct = 0; ct < 2; ++ct) {
        f32x4 acc[4];
#pragma unroll
        for (int rt = 0; rt < 4; ++rt) acc[rt] = (f32x4){0.f, 0.f, 0.f, 0.f};
        const unsigned char* brow = Blds + (ct * 16 + l16) * BROW;
        const int swz = l16 << 4;
#pragma unroll
        for (int rt = 0; rt < 4; ++rt) {
            const f16* hrow = hbuf + (size_t)(rt * 16 + l16) * UNITSN + wv * 512 + lq * 8;
            f16x8 av[16];
#pragma unroll
            for (int kk = 0; kk < 16; ++kk)
                av[kk] = *(const f16x8*)(hrow + kk * 32);
#pragma unroll
            for (int kk = 0; kk < 16; ++kk) {
                const int k0 = wv * 512 + kk * 32 + lq * 8;
                acc[rt] = mfma16(av[kk], *(const f16x8*)(brow + ((2 * k0) ^ swz)), acc[rt]);
            }
            if (wv < 3) {
                const f16x8 ax = *(const f16x8*)(&xlds[rt * 16 + l16][wv * 32 + lq * 8]);
                const int k0 = 2048 + wv * 32 + lq * 8;
                acc[rt] = mfma16(ax, *(const f16x8*)(brow + ((2 * k0) ^ swz)), acc[rt]);
            }
        }
        // serialized cross-wave reduce into red (one-shot kernel; cost trivial)
        if (wv == 0) {
#pragma unroll
            for (int rt = 0; rt < 4; ++rt) *(f32x4*)(&red[rt][lane][0]) = acc[rt];
        }
        __syncthreads();
#pragma unroll
        for (int w = 1; w < 4; ++w) {
            if (wv == w) {
#pragma unroll
                for (int rt = 0; rt < 4; ++rt) {
                    f32x4 cur = *(f32x4*)(&red[rt][lane][0]);
                    cur += acc[rt];
                    *(f32x4*)(&red[rt][lane][0]) = cur;
                }
            }
            __syncthreads();
        }
        // consume: thread -> row r = tid>>2, 4 cols
        {
            const int r = tid >> 2;
            float rsum = 0.f;
#pragma unroll
            for (int q = 0; q < 4; ++q) {
                const int cl = (tid & 3) * 4 + q;
                const int c  = ct * 16 + cl;
                const int lidx = (((r & 15) >> 2) << 4) + cl;
                float v = red[r >> 4][lidx][r & 3] + b5[c0 + c];
                v = tanhf(v);
                rsum += v * Wout[c0 + c];
            }
            rowacc[r][tid & 3] += rsum;
        }
        __syncthreads();
    }
    if (tid < 64) {
        const float s = rowacc[tid][0] + rowacc[tid][1] + rowacc[tid][2] + rowacc[tid][3];
        atomicAdd(&out_pre[tid], s);
    }
}

__global__ void final_out(const float* __restrict__ out_pre,
                          const float* __restrict__ bout, float* __restrict__ out)
{
    const int b = threadIdx.x;
    if (b < BATCHN) out[b] = 1.f / (1.f + expf(-(out_pre[b] + bout[0])));
}

// ---------------------------------------------------------------------------
extern "C" void kernel_launch(void* const* d_in, const int* in_sizes, int n_in,
                              void* d_out, int out_size, void* d_ws, size_t ws_size,
                              hipStream_t stream) {
    (void)in_sizes; (void)n_in; (void)out_size; (void)ws_size;
    const int*   inputs = (const int*)d_in[0];
    const float* emb    = (const float*)d_in[1];
    const float* Wx     = (const float*)d_in[2];
    const float* Wh     = (const float*)d_in[3];
    const float* bias   = (const float*)d_in[4];
    const float* Wout   = (const float*)d_in[5];
    const float* bout   = (const float*)d_in[6];
    float* out = (float*)d_out;

    f16*   hbuf    = (f16*)d_ws;
    int*   flags   = (int*)((char*)d_ws + FLAGS_OFF);
    float* out_pre = (float*)((char*)d_ws + OUTPRE_OFF);

    // reset h state, flag slots, output accumulators (replay-deterministic)
    hipMemsetAsync(d_ws, 0, WS_ZERO_B, stream);

    hipStreamCaptureStatus cs = hipStreamCaptureStatusNone;
    hipStreamIsCapturing(stream, &cs);
    if (cs == hipStreamCaptureStatusActive) {
        rnn_recur<<<dim3(256), dim3(256), 0, stream>>>(inputs, emb, Wx, Wh, bias, hbuf, flags);
    } else {
        void* args[] = {(void*)&inputs, (void*)&emb, (void*)&Wx, (void*)&Wh,
                        (void*)&bias, (void*)&hbuf, (void*)&flags};
        hipError_t e = hipLaunchCooperativeKernel((const void*)rnn_recur, dim3(256), dim3(256),
                                                  args, 0, stream);
        if (e != hipSuccess) {
            rnn_recur<<<dim3(256), dim3(256), 0, stream>>>(inputs, emb, Wx, Wh, bias, hbuf, flags);
        }
    }
    final_gemm<<<dim3(64), dim3(256), 0, stream>>>(inputs, emb, Wx, Wh, bias, Wout, hbuf, out_pre);
    final_out<<<dim3(1), dim3(64), 0, stream>>>(out_pre, bout, out);
}

// Round 4
// 339.312 us; speedup vs baseline: 2.2941x; 1.7148x over previous
//
#include <hip/hip_runtime.h>
#include <math.h>

// Problem constants (from reference)
#define VOCABN 8192
#define EMBN   80
#define UNITSN 2048
#define BATCHN 64
#define SEQN   64

typedef _Float16 f16;
typedef _Float16 f16x8 __attribute__((ext_vector_type(8)));
typedef float    f32x4 __attribute__((ext_vector_type(4)));

// LDS geometry: B-operand slice [32 uu][2176 k] f16, XOR-swizzled rows.
#define BROW 4352  // bytes per uu row; padded so swizzle stays in-row

// ws layout (bytes):
//   [0, 524288)          : hbuf, 2 x [64][2048] f16 (double-buffered h0 state)
//   [524288, 525312)     : flags, 4 groups x 64 WG monotonic step counters
//   [525312, 525568)     : out_pre, 64 floats (pre-sigmoid accumulators)
#define HBUF_BYTES   (2 * BATCHN * UNITSN * 2)
#define FLAGS_OFF    HBUF_BYTES
#define OUTPRE_OFF   (FLAGS_OFF + 4 * 64 * 4)
#define WS_ZERO_B    (OUTPRE_OFF + BATCHN * 4)

__device__ __forceinline__ f32x4 mfma16(f16x8 a, f16x8 b, f32x4 c) {
    return __builtin_amdgcn_mfma_f32_16x16x32_f16(a, b, c, 0, 0, 0);
}

// MALL-coherent (bypass L1+L2) primitives. These are the ONLY way hbuf/flags
// are accessed, so no buffer_inv / buffer_wbl2 is ever needed.
__device__ __forceinline__ void bypass_load_b16(f16x8* dst, const void* p) {
    asm volatile("global_load_dwordx4 %0, %1, off sc0 sc1"
                 : "=v"(*dst) : "v"(p) : "memory");
}
__device__ __forceinline__ int bypass_load_b32(const void* p) {
    int r;
    asm volatile("global_load_dword %0, %1, off sc0 sc1\n\ts_waitcnt vmcnt(0)"
                 : "=v"(r) : "v"(p) : "memory");
    return r;
}
__device__ __forceinline__ void bypass_store_b32(void* p, unsigned int v) {
    asm volatile("global_store_dword %0, %1, off sc0 sc1"
                 :: "v"(p), "v"(v) : "memory");
}
__device__ __forceinline__ void wait_vm0(void) {
    asm volatile("s_waitcnt vmcnt(0)" ::: "memory");
    __builtin_amdgcn_sched_barrier(0);
}

// Load cols [c0,c0+32) of W [2048 x 2048] (+ Wxp [80 x 2048] at k=2048..2143,
// zero-padded to 2144) as f16 into swizzled LDS: byte = uu*BROW + ((2k)^((uu&15)<<4)).
__device__ __forceinline__ void load_wslice(const float* __restrict__ W,
                                            const float* __restrict__ Wxp,
                                            int c0, int tid, unsigned char* Blds)
{
    const int j0 = tid >> 3, l8 = tid & 7;
    for (int it = 0; it < 64; ++it) {
        const int j = j0 + it * 32;
        const float4 w = *(const float4*)(W + (size_t)j * UNITSN + c0 + l8 * 4);
        const float vals[4] = {w.x, w.y, w.z, w.w};
#pragma unroll
        for (int q = 0; q < 4; ++q) {
            const int uu = l8 * 4 + q;
            *(f16*)(Blds + uu * BROW + ((2 * j) ^ ((uu & 15) << 4))) = (f16)vals[q];
        }
    }
    for (int j2 = j0; j2 < 96; j2 += 32) {
        float vals[4] = {0.f, 0.f, 0.f, 0.f};
        if (j2 < EMBN) {
            const float4 w = *(const float4*)(Wxp + (size_t)j2 * UNITSN + c0 + l8 * 4);
            vals[0] = w.x; vals[1] = w.y; vals[2] = w.z; vals[3] = w.w;
        }
#pragma unroll
        for (int q = 0; q < 4; ++q) {
            const int uu = l8 * 4 + q;
            const int k = 2048 + j2;
            *(f16*)(Blds + uu * BROW + ((2 * k) ^ ((uu & 15) << 4))) = (f16)vals[q];
        }
    }
}

// ---------------------------------------------------------------------------
// Recurrent kernel: 256 WGs = 4 row-groups (16 batch rows) x 64 col-chunks.
// Sync v3: all h/flag traffic via sc0+sc1 bypass ops (MALL-coherent);
// zero cache-maintenance instructions in the step loop.
// ---------------------------------------------------------------------------
__global__ __launch_bounds__(256)
void rnn_recur(const int* __restrict__ inputs, const float* __restrict__ emb,
               const float* __restrict__ Wx, const float* __restrict__ Wh,
               const float* __restrict__ bias, f16* __restrict__ hbuf,
               int* __restrict__ flags)
{
    __shared__ unsigned char Blds[32 * BROW];   // 139264 B
    __shared__ f16  xlds[2][16][96];            // 6144 B, double-buffered x_t
    __shared__ float red[4][2][64][4];          // 8192 B, per-wave MFMA partials
    __shared__ int  idxlds[16][SEQN];           // 4096 B, token ids

    const int tid = threadIdx.x;
    const int wg  = blockIdx.x;
    const int g     = wg >> 6;          // row group 0..3
    const int wslot = wg & 63;          // this WG's flag slot within group
    const int c0  = wslot * 32;         // output column base
    const int g16 = g * 16;

    for (int i = tid; i < 16 * SEQN; i += 256)
        idxlds[i >> 6][i & 63] = inputs[(g16 + (i >> 6)) * SEQN + (i & 63)];

    load_wslice(Wh, Wx, c0, tid, Blds);
    __syncthreads();

    // stage x_0
    {
        const int r  = tid >> 4;
        const int kb = (tid & 15) * 6;
        const float* erow = emb + (size_t)idxlds[r][0] * EMBN;
#pragma unroll
        for (int q = 0; q < 6; ++q) {
            const int k = kb + q;
            xlds[0][r][k] = (f16)((k < EMBN) ? erow[k] : 0.f);
        }
    }
    __syncthreads();

    const int lane = tid & 63;
    const int wv   = tid >> 6;      // wave 0..3: K-split
    const int l16  = lane & 15;
    const int lq   = lane >> 4;
    const int rr  = tid >> 4;       // reduce-phase output row 0..15
    const int cpa = (tid & 15) * 2; // reduce-phase output col pair
    const float ba = bias[c0 + cpa];
    const float bb = bias[c0 + cpa + 1];
    const int tla = cpa >> 4;
    const int la  = ((rr >> 2) << 4) + (cpa & 15);
    const int rg  = rr & 3;

    int* gflags = flags + g * 64;

    for (int t = 0; t < SEQN; ++t) {
        const int p = t & 1;   // read buf p, write buf p^1

        // MFMA: acc[16x32] = h_prev @ Wh0 + x_t @ Wx0 (K split by wave).
        // h fragments via bypass loads (coherent at MALL, no fences needed);
        // all 16 issued back-to-back, one vmcnt(0), then MFMA burst.
        f32x4 acc0 = {0.f, 0.f, 0.f, 0.f};
        f32x4 acc1 = {0.f, 0.f, 0.f, 0.f};
        {
            const f16* hrow = hbuf + (size_t)p * BATCHN * UNITSN
                            + (size_t)(g16 + l16) * UNITSN + wv * 512 + lq * 8;
            const int swz = l16 << 4;
            const unsigned char* brow0 = Blds + l16 * BROW;
            const unsigned char* brow1 = Blds + (16 + l16) * BROW;
            f16x8 av[16];
#pragma unroll
            for (int kk = 0; kk < 16; ++kk)
                bypass_load_b16(&av[kk], hrow + kk * 32);
            f16x8 ax;
            if (wv < 3) ax = *(const f16x8*)(&xlds[p][l16][wv * 32 + lq * 8]);
            wait_vm0();
#pragma unroll
            for (int kk = 0; kk < 16; ++kk) {
                const int k0 = wv * 512 + kk * 32 + lq * 8;
                const int bo = (2 * k0) ^ swz;
                acc0 = mfma16(av[kk], *(const f16x8*)(brow0 + bo), acc0);
                acc1 = mfma16(av[kk], *(const f16x8*)(brow1 + bo), acc1);
            }
            if (wv < 3) {
                const int k0 = 2048 + wv * 32 + lq * 8;
                const int bo = (2 * k0) ^ swz;
                acc0 = mfma16(ax, *(const f16x8*)(brow0 + bo), acc0);
                acc1 = mfma16(ax, *(const f16x8*)(brow1 + bo), acc1);
            }
        }
        *(f32x4*)(&red[wv][0][lane][0]) = acc0;
        *(f32x4*)(&red[wv][1][lane][0]) = acc1;
        __syncthreads();

        // reduce 4 waves, bias, tanh, packed bypass store
        {
            float va = ba, vb = bb;
#pragma unroll
            for (int w = 0; w < 4; ++w) {
                va += red[w][tla][la][rg];
                vb += red[w][tla][la + 1][rg];
            }
            const f16 ha = (f16)tanhf(va);
            const f16 hb = (f16)tanhf(vb);
            const unsigned int pk = (unsigned int)__builtin_bit_cast(unsigned short, ha)
                                  | ((unsigned int)__builtin_bit_cast(unsigned short, hb) << 16);
            unsigned int* dst = (unsigned int*)(hbuf + (size_t)(p ^ 1) * BATCHN * UNITSN
                                                + (size_t)(g16 + rr) * UNITSN + c0 + cpa);
            bypass_store_b32(dst, pk);
        }
        // per-thread drain: h store acked at MALL before anyone passes barrier
        asm volatile("s_waitcnt vmcnt(0)" ::: "memory");
        __syncthreads();

        if (t == SEQN - 1) break;   // final h0 now in hbuf[0]

        // publish: own slot, monotonic value, bypass store (no wbl2)
        if (tid == 0)
            bypass_store_b32(&gflags[wslot], (unsigned int)(t + 1));

        // overlap: stage x_{t+1} (plain cached loads; L1/L2 never invalidated)
        {
            const int r  = tid >> 4;
            const int kb = (tid & 15) * 6;
            const float* erow = emb + (size_t)idxlds[r][t + 1] * EMBN;
            const int buf = (t + 1) & 1;
#pragma unroll
            for (int q = 0; q < 6; ++q) {
                const int k = kb + q;
                xlds[buf][r][k] = (f16)((k < EMBN) ? erow[k] : 0.f);
            }
        }

        // wave-0 poll: one 64-lane bypass load per round; no acquire fence
        if (wv == 0) {
            int tries = 0;
            for (;;) {
                const int v = bypass_load_b32(&gflags[lane]);
                if (__all(v > t)) break;
                __builtin_amdgcn_s_sleep(1);
                if (++tries > 150000) break;   // safety valve
            }
        }
        __syncthreads();   // releases waves 1..3; xlds[t+1] also ready
    }
}

// ---------------------------------------------------------------------------
// Final layer-5 at t=63 via MFMA: 64 WGs, each 32 cols x all 64 batch rows.
// h5 = tanh(x63@Wx5 + h0@Wh5 + b5); out_pre[r] += h5 . Wout (atomicAdd).
// ---------------------------------------------------------------------------
__global__ __launch_bounds__(256)
void final_gemm(const int* __restrict__ inputs, const float* __restrict__ emb,
                const float* __restrict__ Wx, const float* __restrict__ Wh,
                const float* __restrict__ bias, const float* __restrict__ Wout,
                const f16* __restrict__ hbuf, float* __restrict__ out_pre)
{
    __shared__ unsigned char Blds[32 * BROW];   // 139264 B
    __shared__ f16  xlds[64][96];               // 12288 B
    __shared__ float red[4][64][4];             // 4096 B (one col-tile pass)
    __shared__ float rowacc[64][4];             // 1024 B

    const int tid = threadIdx.x;
    const int c0  = blockIdx.x * 32;
    const float* Wh5 = Wh + (size_t)5 * UNITSN * UNITSN;
    const float* Wx5 = Wx + (size_t)5 * EMBN * UNITSN;
    const float* b5  = bias + 5 * UNITSN;

    load_wslice(Wh5, Wx5, c0, tid, Blds);
    // stage x_63 for all 64 rows
    {
        const int r  = tid >> 2;
        const int kb = (tid & 3) * 24;
        const float* erow = emb + (size_t)inputs[r * SEQN + SEQN - 1] * EMBN;
#pragma unroll
        for (int q = 0; q < 24; ++q) {
            const int k = kb + q;
            xlds[r][k] = (f16)((k < EMBN) ? erow[k] : 0.f);
        }
    }
    rowacc[tid >> 2][tid & 3] = 0.f;
    __syncthreads();

    const int lane = tid & 63;
    const int wv   = tid >> 6;
    const int l16  = lane & 15;
    const int lq   = lane >> 4;

    for (int ct = 0; ct < 2; ++ct) {
        f32x4 acc[4];
#pragma unroll
        for (int rt = 0; rt < 4; ++rt) acc[rt] = (f32x4){0.f, 0.f, 0.f, 0.f};
        const unsigned char* brow = Blds + (ct * 16 + l16) * BROW;
        const int swz = l16 << 4;
#pragma unroll
        for (int rt = 0; rt < 4; ++rt) {
            const f16* hrow = hbuf + (size_t)(rt * 16 + l16) * UNITSN + wv * 512 + lq * 8;
            f16x8 av[16];
#pragma unroll
            for (int kk = 0; kk < 16; ++kk)
                bypass_load_b16(&av[kk], hrow + kk * 32);   // stale-L2-proof
            f16x8 ax;
            if (wv < 3) ax = *(const f16x8*)(&xlds[rt * 16 + l16][wv * 32 + lq * 8]);
            wait_vm0();
#pragma unroll
            for (int kk = 0; kk < 16; ++kk) {
                const int k0 = wv * 512 + kk * 32 + lq * 8;
                acc[rt] = mfma16(av[kk], *(const f16x8*)(brow + ((2 * k0) ^ swz)), acc[rt]);
            }
            if (wv < 3) {
                const int k0 = 2048 + wv * 32 + lq * 8;
                acc[rt] = mfma16(ax, *(const f16x8*)(brow + ((2 * k0) ^ swz)), acc[rt]);
            }
        }
        // serialized cross-wave reduce into red (one-shot kernel; cost trivial)
        if (wv == 0) {
#pragma unroll
            for (int rt = 0; rt < 4; ++rt) *(f32x4*)(&red[rt][lane][0]) = acc[rt];
        }
        __syncthreads();
#pragma unroll
        for (int w = 1; w < 4; ++w) {
            if (wv == w) {
#pragma unroll
                for (int rt = 0; rt < 4; ++rt) {
                    f32x4 cur = *(f32x4*)(&red[rt][lane][0]);
                    cur += acc[rt];
                    *(f32x4*)(&red[rt][lane][0]) = cur;
                }
            }
            __syncthreads();
        }
        // consume: thread -> row r = tid>>2, 4 cols
        {
            const int r = tid >> 2;
            float rsum = 0.f;
#pragma unroll
            for (int q = 0; q < 4; ++q) {
                const int cl = (tid & 3) * 4 + q;
                const int c  = ct * 16 + cl;
                const int lidx = (((r & 15) >> 2) << 4) + cl;
                float v = red[r >> 4][lidx][r & 3] + b5[c0 + c];
                v = tanhf(v);
                rsum += v * Wout[c0 + c];
            }
            rowacc[r][tid & 3] += rsum;
        }
        __syncthreads();
    }
    if (tid < 64) {
        const float s = rowacc[tid][0] + rowacc[tid][1] + rowacc[tid][2] + rowacc[tid][3];
        atomicAdd(&out_pre[tid], s);
    }
}

__global__ void final_out(const float* __restrict__ out_pre,
                          const float* __restrict__ bout, float* __restrict__ out)
{
    const int b = threadIdx.x;
    if (b < BATCHN) out[b] = 1.f / (1.f + expf(-(out_pre[b] + bout[0])));
}

// ---------------------------------------------------------------------------
extern "C" void kernel_launch(void* const* d_in, const int* in_sizes, int n_in,
                              void* d_out, int out_size, void* d_ws, size_t ws_size,
                              hipStream_t stream) {
    (void)in_sizes; (void)n_in; (void)out_size; (void)ws_size;
    const int*   inputs = (const int*)d_in[0];
    const float* emb    = (const float*)d_in[1];
    const float* Wx     = (const float*)d_in[2];
    const float* Wh     = (const float*)d_in[3];
    const float* bias   = (const float*)d_in[4];
    const float* Wout   = (const float*)d_in[5];
    const float* bout   = (const float*)d_in[6];
    float* out = (float*)d_out;

    f16*   hbuf    = (f16*)d_ws;
    int*   flags   = (int*)((char*)d_ws + FLAGS_OFF);
    float* out_pre = (float*)((char*)d_ws + OUTPRE_OFF);

    // reset h state, flag slots, output accumulators (replay-deterministic)
    (void)hipMemsetAsync(d_ws, 0, WS_ZERO_B, stream);

    hipStreamCaptureStatus cs = hipStreamCaptureStatusNone;
    (void)hipStreamIsCapturing(stream, &cs);
    if (cs == hipStreamCaptureStatusActive) {
        rnn_recur<<<dim3(256), dim3(256), 0, stream>>>(inputs, emb, Wx, Wh, bias, hbuf, flags);
    } else {
        void* args[] = {(void*)&inputs, (void*)&emb, (void*)&Wx, (void*)&Wh,
                        (void*)&bias, (void*)&hbuf, (void*)&flags};
        hipError_t e = hipLaunchCooperativeKernel((const void*)rnn_recur, dim3(256), dim3(256),
                                                  args, 0, stream);
        if (e != hipSuccess) {
            rnn_recur<<<dim3(256), dim3(256), 0, stream>>>(inputs, emb, Wx, Wh, bias, hbuf, flags);
        }
    }
    final_gemm<<<dim3(64), dim3(256), 0, stream>>>(inputs, emb, Wx, Wh, bias, Wout, hbuf, out_pre);
    final_out<<<dim3(1), dim3(64), 0, stream>>>(out_pre, bout, out);
}